// Round 3
// baseline (2710.158 us; speedup 1.0000x reference)
//
#include <hip/hip_runtime.h>

#define Bq 8
#define Nq 8192
#define NPOINT 1024
#define NSAMPLE 32
#define DF 64
#define RAD2 0.0625f
#define FPS_T 256
#define FPS_PPT (Nq / FPS_T) /* 32 */

// ---------------------------------------------------------------------------
// Kernel 1: farthest point sampling, one block (256 thr, 4 waves) per batch.
// Bit-exact: d = ((dx*dx)+(dy*dy))+(dz*dz) plain chain (contract off), min,
// first-occurrence argmax (strided ascending ownership + tie->min index).
// One barrier per iteration: per-wave butterfly BEFORE the barrier, packed
// u64 (d_bits<<32 | ~i) per-wave bests in double-buffered LDS, then every
// thread redundantly reduces the 4 entries (max u64 == max d, tie min i;
// valid since d >= 0 so f32 bit pattern is order-monotone).
// ---------------------------------------------------------------------------
__global__ void __launch_bounds__(FPS_T, 1)
fps_kernel(const float* __restrict__ xyz, float* __restrict__ new_xyz)
{
#pragma clang fp contract(off)
    extern __shared__ float lds[];
    float2* xy = (float2*)lds;          // 8192 float2 = 64 KB
    float*  zz = lds + 2 * Nq;          // 32 KB
    __shared__ unsigned long long wbest[2][FPS_T / 64];

    const int b    = blockIdx.x;
    const int t    = threadIdx.x;
    const int lane = t & 63;
    const int wid  = t >> 6;
    const float* xb = xyz + (size_t)b * Nq * 3;

    for (int i = t; i < Nq; i += FPS_T) {
        const float x = xb[i * 3 + 0];
        const float y = xb[i * 3 + 1];
        const float z = xb[i * 3 + 2];
        xy[i] = make_float2(x, y);
        zz[i] = z;
    }
    __syncthreads();

    float dist[FPS_PPT];
#pragma unroll
    for (int j = 0; j < FPS_PPT; ++j) dist[j] = 1e10f;

    int farthest = 0;
    float* ob = new_xyz + (size_t)b * NPOINT * 3;

    for (int it = 0; it < NPOINT; ++it) {
        const float2 cxy = xy[farthest];
        const float  cz  = zz[farthest];
        const float  cx  = cxy.x;
        const float  cy  = cxy.y;
        if (t == 0) {
            ob[it * 3 + 0] = cx;
            ob[it * 3 + 1] = cy;
            ob[it * 3 + 2] = cz;
        }
        float bv = -1.0f;
        int   bi = Nq;
#pragma unroll
        for (int j = 0; j < FPS_PPT; ++j) {
            const int i = t + j * FPS_T;           // ascending per thread
            const float2 p = xy[i];
            const float dx = p.x - cx;
            const float dy = p.y - cy;
            const float dz = zz[i] - cz;
            const float d  = dx * dx + dy * dy + dz * dz;  // no-FMA, L-to-R
            const float nd = fminf(dist[j], d);
            dist[j] = nd;
            if (nd > bv) { bv = nd; bi = i; }      // strict > keeps first max
        }
        // intra-wave butterfly reduce: max value, tie -> min index
#pragma unroll
        for (int off = 32; off > 0; off >>= 1) {
            const float ov = __shfl_xor(bv, off, 64);
            const int   oi = __shfl_xor(bi, off, 64);
            if (ov > bv || (ov == bv && oi < bi)) { bv = ov; bi = oi; }
        }
        if (lane == 0) {
            wbest[it & 1][wid] =
                ((unsigned long long)__float_as_uint(bv) << 32) |
                (unsigned int)(~bi);
        }
        __syncthreads();
        unsigned long long best = wbest[it & 1][0];
#pragma unroll
        for (int w = 1; w < FPS_T / 64; ++w) {
            const unsigned long long k = wbest[it & 1][w];
            if (k > best) best = k;
        }
        farthest = (int)(~(unsigned int)(best & 0xffffffffull));
    }
}

// ---------------------------------------------------------------------------
// Kernel 2: ball query, one wave (64 lanes) per query.
// Reference formula: d = ((-2*dot(q,p)) + |q|^2) + |p|^2 with the K=3 dot as
// an FMA chain (Eigen GEMM lowering); norms are plain mul/add reduces.
// Collect the first NSAMPLE indices in ascending order via ballot prefix.
// ---------------------------------------------------------------------------
__global__ void __launch_bounds__(256, 4)
ballq_kernel(const float* __restrict__ xyz, const float* __restrict__ new_xyz,
             int* __restrict__ ball_idx)
{
#pragma clang fp contract(off)
    __shared__ int sel[4][NSAMPLE];
    const int w    = threadIdx.x >> 6;
    const int lane = threadIdx.x & 63;
    const int wq   = blockIdx.x * 4 + w;      // global query id, < Bq*NPOINT
    const int b    = wq >> 10;                // / NPOINT

    const float qx = new_xyz[wq * 3 + 0];
    const float qy = new_xyz[wq * 3 + 1];
    const float qz = new_xyz[wq * 3 + 2];
    const float ssrc = qx * qx + qy * qy + qz * qz;   // plain chain
    const float* xb = xyz + (size_t)b * Nq * 3;

    int cnt = 0;
    for (int base = 0; base < Nq; base += 64) {
        const int i = base + lane;
        const float px = xb[i * 3 + 0];
        const float py = xb[i * 3 + 1];
        const float pz = xb[i * 3 + 2];
        const float dot  = __builtin_fmaf(pz, qz, __builtin_fmaf(py, qy, px * qx));
        const float sdst = px * px + py * py + pz * pz;           // plain chain
        const float d    = (-2.0f * dot + ssrc) + sdst;
        const bool  in   = (d <= RAD2);
        const unsigned long long m = __ballot(in);
        if (in) {
            const int slot = cnt + (int)__popcll(m & ((1ull << lane) - 1ull));
            if (slot < NSAMPLE) sel[w][slot] = i;
        }
        cnt += (int)__popcll(m);
        if (cnt >= NSAMPLE) break;
    }
    // pad with first index (query point itself guarantees cnt >= 1)
    const int first = sel[w][0];
    if (cnt < NSAMPLE) {
        for (int s = cnt + lane; s < NSAMPLE; s += 64) sel[w][s] = first;
    }
    if (lane < NSAMPLE) ball_idx[(size_t)wq * NSAMPLE + lane] = sel[w][lane];
}

// ---------------------------------------------------------------------------
// Kernel 3: gather + concat -> new_points (B, NPOINT, NSAMPLE, 3+DF).
// One thread per output element; coalesced writes.
// ---------------------------------------------------------------------------
__global__ void __launch_bounds__(256)
fill_kernel(const float* __restrict__ xyz, const float* __restrict__ points,
            const float* __restrict__ new_xyz, const int* __restrict__ ball_idx,
            float* __restrict__ new_points)
{
#pragma clang fp contract(off)
    const int TOT = Bq * NPOINT * NSAMPLE * (3 + DF);
    const int t = blockIdx.x * 256 + threadIdx.x;
    if (t >= TOT) return;
    const int c  = t % (3 + DF);
    const int g  = t / (3 + DF);        // (b*NPOINT+q)*NSAMPLE + s
    const int bq = g >> 5;              // / NSAMPLE
    const int b  = bq >> 10;            // / NPOINT
    const int idx = ball_idx[g];
    float v;
    if (c < 3) {
        v = xyz[((size_t)b * Nq + idx) * 3 + c] - new_xyz[(size_t)bq * 3 + c];
    } else {
        v = points[((size_t)b * Nq + idx) * DF + (c - 3)];
    }
    new_points[t] = v;
}

// ---------------------------------------------------------------------------
extern "C" void kernel_launch(void* const* d_in, const int* in_sizes, int n_in,
                              void* d_out, int out_size, void* d_ws, size_t ws_size,
                              hipStream_t stream)
{
    (void)in_sizes; (void)n_in; (void)out_size; (void)ws_size;
    const float* xyz    = (const float*)d_in[0];
    const float* points = (const float*)d_in[1];
    float* out        = (float*)d_out;
    float* new_xyz    = out;                               // Bq*NPOINT*3
    float* new_points = out + (size_t)Bq * NPOINT * 3;     // rest
    int*   ball_idx   = (int*)d_ws;                        // Bq*NPOINT*NSAMPLE

    hipFuncSetAttribute(reinterpret_cast<const void*>(fps_kernel),
                        hipFuncAttributeMaxDynamicSharedMemorySize,
                        3 * Nq * (int)sizeof(float));

    fps_kernel<<<Bq, FPS_T, 3 * Nq * sizeof(float), stream>>>(xyz, new_xyz);
    ballq_kernel<<<(Bq * NPOINT) / 4, 256, 0, stream>>>(xyz, new_xyz, ball_idx);
    const int TOT = Bq * NPOINT * NSAMPLE * (3 + DF);
    fill_kernel<<<(TOT + 255) / 256, 256, 0, stream>>>(xyz, points, new_xyz,
                                                       ball_idx, new_points);
}

// Round 4
// 1741.053 us; speedup vs baseline: 1.5566x; 1.5566x over previous
//
#include <hip/hip_runtime.h>

#define Bq 8
#define Nq 8192
#define NPOINT 1024
#define NSAMPLE 32
#define DF 64
#define RAD2 0.0625f
#define FPS_T 1024
#define FPS_PPT (Nq / FPS_T) /* 8 */

// ---------------------------------------------------------------------------
// Kernel 1: FPS, one block (1024 thr, 16 waves) per batch.
// Points live in REGISTERS (ppt=8): inner loop is pure VALU, no LDS reads.
// LDS holds a float4 table only for the once-per-iter centroid lookup, done
// by wave 0 inside its reduce tail and broadcast via s_cent.
// Bit-exact: d = ((dx*dx)+(dy*dy))+(dz*dz) plain chain (contract off), min,
// first-occurrence argmax (ascending per-thread idx, strict >, cross-lane
// tie -> min index; packed u64 (d_bits<<32 | ~i) so max == (max d, min i)).
// ---------------------------------------------------------------------------
__global__ void __launch_bounds__(FPS_T, 1)
fps_kernel(const float* __restrict__ xyz, float* __restrict__ new_xyz)
{
#pragma clang fp contract(off)
    extern __shared__ float lds[];
    float4* tab = (float4*)lds;                     // 8192 * 16B = 128 KB
    __shared__ unsigned long long wbest[FPS_T / 64];
    __shared__ float4 s_cent;

    const int b    = blockIdx.x;
    const int t    = threadIdx.x;
    const int lane = t & 63;
    const int wid  = t >> 6;
    const float* xb = xyz + (size_t)b * Nq * 3;

    float px[FPS_PPT], py[FPS_PPT], pz[FPS_PPT];
#pragma unroll
    for (int j = 0; j < FPS_PPT; ++j) {
        const int i = t + j * FPS_T;
        const float x = xb[i * 3 + 0];
        const float y = xb[i * 3 + 1];
        const float z = xb[i * 3 + 2];
        px[j] = x; py[j] = y; pz[j] = z;
        tab[i] = make_float4(x, y, z, 0.0f);
    }
    if (t == 0) s_cent = make_float4(px[0], py[0], pz[0], 0.0f);
    __syncthreads();

    float dist[FPS_PPT];
#pragma unroll
    for (int j = 0; j < FPS_PPT; ++j) dist[j] = 1e10f;

    float* ob = new_xyz + (size_t)b * NPOINT * 3;

    for (int it = 0; it < NPOINT; ++it) {
        const float4 c = s_cent;                    // ds_read_b128 broadcast
        if (t == 64) {                              // wave 1 writes output
            ob[it * 3 + 0] = c.x;
            ob[it * 3 + 1] = c.y;
            ob[it * 3 + 2] = c.z;
        }
        float bv = -1.0f;
        int   bi = Nq;
#pragma unroll
        for (int j = 0; j < FPS_PPT; ++j) {
            const float dx = px[j] - c.x;
            const float dy = py[j] - c.y;
            const float dz = pz[j] - c.z;
            const float d  = dx * dx + dy * dy + dz * dz;  // no-FMA, L-to-R
            const float nd = fminf(dist[j], d);
            dist[j] = nd;
            if (nd > bv) { bv = nd; bi = t + j * FPS_T; }  // strict >, asc idx
        }
        // intra-wave butterfly: max value, tie -> min index
#pragma unroll
        for (int off = 32; off > 0; off >>= 1) {
            const float ov = __shfl_xor(bv, off, 64);
            const int   oi = __shfl_xor(bi, off, 64);
            if (ov > bv || (ov == bv && oi < bi)) { bv = ov; bi = oi; }
        }
        if (lane == 0) {
            wbest[wid] = ((unsigned long long)__float_as_uint(bv) << 32) |
                         (unsigned int)(~bi);
        }
        __syncthreads();
        if (wid == 0) {
            // 16 entries replicated 4x across 64 lanes -> 4 butterfly steps
            unsigned long long k = wbest[lane & 15];
#pragma unroll
            for (int off = 8; off > 0; off >>= 1) {
                const unsigned long long ok = __shfl_xor(k, off, 64);
                if (ok > k) k = ok;
            }
            const int far = (int)(~(unsigned int)(k & 0xffffffffull));
            const float4 nc = tab[far];             // uniform addr broadcast
            if (lane == 0) s_cent = nc;
        }
        __syncthreads();
    }
}

// ---------------------------------------------------------------------------
// Kernel 2: ball query, one wave per query (unchanged, verified absmax 0).
// ---------------------------------------------------------------------------
__global__ void __launch_bounds__(256, 4)
ballq_kernel(const float* __restrict__ xyz, const float* __restrict__ new_xyz,
             int* __restrict__ ball_idx)
{
#pragma clang fp contract(off)
    __shared__ int sel[4][NSAMPLE];
    const int w    = threadIdx.x >> 6;
    const int lane = threadIdx.x & 63;
    const int wq   = blockIdx.x * 4 + w;
    const int b    = wq >> 10;

    const float qx = new_xyz[wq * 3 + 0];
    const float qy = new_xyz[wq * 3 + 1];
    const float qz = new_xyz[wq * 3 + 2];
    const float ssrc = qx * qx + qy * qy + qz * qz;   // plain chain
    const float* xb = xyz + (size_t)b * Nq * 3;

    int cnt = 0;
    for (int base = 0; base < Nq; base += 64) {
        const int i = base + lane;
        const float px = xb[i * 3 + 0];
        const float py = xb[i * 3 + 1];
        const float pz = xb[i * 3 + 2];
        const float dot  = __builtin_fmaf(pz, qz, __builtin_fmaf(py, qy, px * qx));
        const float sdst = px * px + py * py + pz * pz;           // plain chain
        const float d    = (-2.0f * dot + ssrc) + sdst;
        const bool  in   = (d <= RAD2);
        const unsigned long long m = __ballot(in);
        if (in) {
            const int slot = cnt + (int)__popcll(m & ((1ull << lane) - 1ull));
            if (slot < NSAMPLE) sel[w][slot] = i;
        }
        cnt += (int)__popcll(m);
        if (cnt >= NSAMPLE) break;
    }
    const int first = sel[w][0];
    if (cnt < NSAMPLE) {
        for (int s = cnt + lane; s < NSAMPLE; s += 64) sel[w][s] = first;
    }
    if (lane < NSAMPLE) ball_idx[(size_t)wq * NSAMPLE + lane] = sel[w][lane];
}

// ---------------------------------------------------------------------------
// Kernel 3: gather + concat (unchanged, verified absmax 0).
// ---------------------------------------------------------------------------
__global__ void __launch_bounds__(256)
fill_kernel(const float* __restrict__ xyz, const float* __restrict__ points,
            const float* __restrict__ new_xyz, const int* __restrict__ ball_idx,
            float* __restrict__ new_points)
{
#pragma clang fp contract(off)
    const int TOT = Bq * NPOINT * NSAMPLE * (3 + DF);
    const int t = blockIdx.x * 256 + threadIdx.x;
    if (t >= TOT) return;
    const int c  = t % (3 + DF);
    const int g  = t / (3 + DF);
    const int bq = g >> 5;
    const int b  = bq >> 10;
    const int idx = ball_idx[g];
    float v;
    if (c < 3) {
        v = xyz[((size_t)b * Nq + idx) * 3 + c] - new_xyz[(size_t)bq * 3 + c];
    } else {
        v = points[((size_t)b * Nq + idx) * DF + (c - 3)];
    }
    new_points[t] = v;
}

// ---------------------------------------------------------------------------
extern "C" void kernel_launch(void* const* d_in, const int* in_sizes, int n_in,
                              void* d_out, int out_size, void* d_ws, size_t ws_size,
                              hipStream_t stream)
{
    (void)in_sizes; (void)n_in; (void)out_size; (void)ws_size;
    const float* xyz    = (const float*)d_in[0];
    const float* points = (const float*)d_in[1];
    float* out        = (float*)d_out;
    float* new_xyz    = out;                               // Bq*NPOINT*3
    float* new_points = out + (size_t)Bq * NPOINT * 3;     // rest
    int*   ball_idx   = (int*)d_ws;                        // Bq*NPOINT*NSAMPLE

    hipFuncSetAttribute(reinterpret_cast<const void*>(fps_kernel),
                        hipFuncAttributeMaxDynamicSharedMemorySize,
                        Nq * (int)sizeof(float4));

    fps_kernel<<<Bq, FPS_T, Nq * sizeof(float4), stream>>>(xyz, new_xyz);
    ballq_kernel<<<(Bq * NPOINT) / 4, 256, 0, stream>>>(xyz, new_xyz, ball_idx);
    const int TOT = Bq * NPOINT * NSAMPLE * (3 + DF);
    fill_kernel<<<(TOT + 255) / 256, 256, 0, stream>>>(xyz, points, new_xyz,
                                                       ball_idx, new_points);
}